// Round 3
// baseline (430.264 us; speedup 1.0000x reference)
//
#include <hip/hip_runtime.h>

#define N_ROWS 32768
#define DIMS 256
#define K_CODES 1024
#define MT 128     // rows per block
#define NCHUNK 256 // codes per chunk
#define KC 32      // K per LDS stage
#define SA 132     // As stride: 128 rows + 4 pad
#define SB 260     // Bs stride: 256 codes + 4 pad

static constexpr size_t SC_OFF  = 8388608;   // after quantized [32768*256] (float32 elements)
static constexpr size_t IDX_OFF = 8388612;   // after 4 scalars

__device__ inline float wsum64(float v){
  #pragma unroll
  for(int off=32; off; off>>=1) v += __shfl_xor(v, off, 64);
  return v;
}

// ---- row squared norm: bit-exact numpy AVX512 SIMD pairwise emulation ------
// np.sum(a*a, -1), n=256: pairwise split 128+128; per 128-block 8 vector
// accumulators lanewise-combined, then (+8)(+4)(+2)(+1) butterfly. Squares
// rounded before summing; __fmul_rn/__fadd_rn forbid FMA contraction.
// noinline: called 5x in the prologue; keeps the hot loop's I$ footprint small.
__device__ __attribute__((noinline)) float rowsq_np512(const float* __restrict__ s0){
  float blk[2];
  #pragma unroll
  for(int bb=0; bb<2; bb++){
    const float* s = s0 + bb*128;
    float q[128];
    #pragma unroll
    for(int i=0;i<32;i++){
      float4 v = *(const float4*)(s + i*4);
      q[i*4+0]=__fmul_rn(v.x,v.x); q[i*4+1]=__fmul_rn(v.y,v.y);
      q[i*4+2]=__fmul_rn(v.z,v.z); q[i*4+3]=__fmul_rn(v.w,v.w);
    }
    float v16[16];
    #pragma unroll
    for(int l=0;l<16;l++)
      v16[l] = __fadd_rn(__fadd_rn(__fadd_rn(q[l],     q[l+16]),
                                   __fadd_rn(q[l+32],  q[l+48])),
                         __fadd_rn(__fadd_rn(q[l+64],  q[l+80]),
                                   __fadd_rn(q[l+96],  q[l+112])));
    float w8[8];
    #pragma unroll
    for(int l=0;l<8;l++) w8[l] = __fadd_rn(v16[l], v16[l+8]);
    float u4[4];
    #pragma unroll
    for(int l=0;l<4;l++) u4[l] = __fadd_rn(w8[l], w8[l+4]);
    float t0 = __fadd_rn(u4[0], u4[2]);
    float t1 = __fadd_rn(u4[1], u4[3]);
    blk[bb] = __fadd_rn(t0, t1);
  }
  return __fadd_rn(blk[0], blk[1]);
}

// --------- fused: norms + distances + argmin + softmax + quant gather -------
// LDS-instruction-throughput redesign (R3):
//  * 8 rows x 16 codes per thread: per k, 2 b128 (A) + 4 b128 (B) = 6 LDS
//    instr per 128 FMAs (was 5 per 64) -> LDS-read pipe 205us -> ~123us,
//    at the 109us FMA-issue floor.
//  * MT=128, grid 256, 1 block/CU, 4 waves. All k-major LDS reads/writes
//    <=2-way per bank (free). Row norms computed in-prologue (exact helper).
// The per-(row,code) single-accumulator ascending-k fmaf chain is unchanged
// -> distances remain bit-exact vs the CPU BLAS reference.
__global__ __launch_bounds__(256,1) void fused_argmin_kernel(
    const float* __restrict__ X, const float* __restrict__ CB,
    float* __restrict__ hist, float* __restrict__ acc_sc,
    float* __restrict__ out)
{
  __shared__ __align__(16) float As[KC][SA];
  __shared__ __align__(16) float Bs[KC][SB];
  __shared__ __align__(16) float cs_lds[K_CODES];
  __shared__ __align__(16) float xs_lds[MT];
  __shared__ int sk[MT];
  const int t  = threadIdx.x;
  const int tx = t & 15, ty = t >> 4;     // 16 tx (codes) x 16 ty (8 rows each)
  const int m0 = blockIdx.x * MT;

  // ---- prologue: row norms (bit-exact numpy emulation) into LDS -----------
  for(int c=0;c<4;c++)
    cs_lds[c*256 + t] = rowsq_np512(CB + (size_t)(c*256 + t)*DIMS);
  if(t < MT)
    xs_lds[t] = rowsq_np512(X + (size_t)(m0 + t)*DIMS);

  const int arow = t >> 1;            // 0..127 : row within tile
  const int acol = (t & 1) * 16;      // 0/16   : k offset (16 floats per thread)
  const float* Ag = X + (size_t)(m0 + arow)*DIMS + acol;

  // stage-0 register prefetch (nc=0, kc=0); overlaps the barrier
  float4 a4p[4], b4p[8];
  #pragma unroll
  for(int q=0;q<4;q++) a4p[q] = *(const float4*)(Ag + q*4);
  {
    const float* Bg = CB + (size_t)t*DIMS;   // code t of chunk 0
    #pragma unroll
    for(int q=0;q<8;q++) b4p[q] = *(const float4*)(Bg + q*4);
  }
  __syncthreads();                    // cs_lds/xs_lds ready

  float xs_[8];
  { float4 x0 = *(const float4*)&xs_lds[ty*8];
    float4 x1 = *(const float4*)&xs_lds[ty*8+4];
    xs_[0]=x0.x; xs_[1]=x0.y; xs_[2]=x0.z; xs_[3]=x0.w;
    xs_[4]=x1.x; xs_[5]=x1.y; xs_[6]=x1.z; xs_[7]=x1.w; }

  // per-thread online state for rows ty*8 + {0..7}
  float dm[8]; int km[8]; float Ss[8], Ts[8];

  for(int nc=0; nc<4; nc++){
    const int n0c = nc*NCHUNK;
    float acc[8][16];
    #pragma unroll
    for(int i=0;i<8;i++)
      #pragma unroll
      for(int j=0;j<16;j++) acc[i][j]=0.f;

    // K-chain: strictly ascending k=0..255, one fmaf chain per (row,code)
    for(int kc=0;kc<8;kc++){
      __syncthreads();
      // commit prefetched stage to LDS (k-major scatter; 2-way max = free)
      #pragma unroll
      for(int q=0;q<4;q++){
        As[acol+q*4+0][arow]=a4p[q].x; As[acol+q*4+1][arow]=a4p[q].y;
        As[acol+q*4+2][arow]=a4p[q].z; As[acol+q*4+3][arow]=a4p[q].w;
      }
      #pragma unroll
      for(int q=0;q<8;q++){
        Bs[q*4+0][t]=b4p[q].x; Bs[q*4+1][t]=b4p[q].y;
        Bs[q*4+2][t]=b4p[q].z; Bs[q*4+3][t]=b4p[q].w;
      }
      __syncthreads();
      // prefetch next stage; latency hides under the 4096-FMA compute phase
      {
        int nkc = kc+1, nnc = nc;
        if(nkc==8){ nkc=0; nnc=(nc+1)&3; }
        const float* An = Ag + nkc*KC;
        const float* Bn = CB + (size_t)(nnc*NCHUNK + t)*DIMS + nkc*KC;
        #pragma unroll
        for(int q=0;q<4;q++) a4p[q]=*(const float4*)(An + q*4);
        #pragma unroll
        for(int q=0;q<8;q++) b4p[q]=*(const float4*)(Bn + q*4);
      }
      #pragma unroll 8
      for(int k=0;k<KC;k++){
        float4 a0 = *(const float4*)&As[k][ty*8];
        float4 a1 = *(const float4*)&As[k][ty*8+4];
        float4 b0 = *(const float4*)&Bs[k][tx*4];
        float4 b1 = *(const float4*)&Bs[k][64  + tx*4];
        float4 b2 = *(const float4*)&Bs[k][128 + tx*4];
        float4 b3 = *(const float4*)&Bs[k][192 + tx*4];
        float a_[8]={a0.x,a0.y,a0.z,a0.w, a1.x,a1.y,a1.z,a1.w};
        float b_[16]={b0.x,b0.y,b0.z,b0.w, b1.x,b1.y,b1.z,b1.w,
                      b2.x,b2.y,b2.z,b2.w, b3.x,b3.y,b3.z,b3.w};
        #pragma unroll
        for(int r=0;r<8;r++)
          #pragma unroll
          for(int j=0;j<16;j++)
            acc[r][j] = fmaf(a_[r], b_[j], acc[r][j]);
      }
    }

    // ---- chunk epilogue: d = sqrt(max(fl(fl(xs+cs) - 2*dot), 0)) -----------
    float csv[16];
    #pragma unroll
    for(int g=0;g<4;g++){
      float4 c4 = *(const float4*)&cs_lds[n0c + g*64 + tx*4];
      csv[g*4+0]=c4.x; csv[g*4+1]=c4.y; csv[g*4+2]=c4.z; csv[g*4+3]=c4.w;
    }
    #pragma unroll
    for(int i=0;i<8;i++){
      float xs = xs_[i];
      float d[16];
      #pragma unroll
      for(int j=0;j<16;j++){
        // contraction-safe: 2*acc exact, fl(t - 2*acc)
        float d2 = (xs + csv[j]) - 2.0f*acc[i][j];
        d[j] = sqrtf(fmaxf(d2, 0.f));
      }
      // thread-local argmin, ascending kidx, strict < (first-occurrence tie)
      float dl = INFINITY; int kl = 0;
      #pragma unroll
      for(int j=0;j<16;j++){
        int kidx = n0c + (j>>2)*64 + tx*4 + (j&3);   // ascending in j
        if(d[j] < dl){ dl = d[j]; kl = kidx; }
      }
      // butterfly across the 16 tx lanes of this row group
      #pragma unroll
      for(int off=1; off<16; off<<=1){
        float od = __shfl_xor(dl, off, 64);
        int   ok = __shfl_xor(kl, off, 64);
        if(od < dl || (od == dl && ok < kl)){ dl = od; kl = ok; }
      }
      // chunk softmax stats shifted at chunk min: l = (dl - d)*100 <= 0
      float s1=0.f, t2s=0.f;
      #pragma unroll
      for(int j=0;j<16;j++){
        float l = (dl - d[j])*100.0f;
        float e = expf(l);
        s1 += e; t2s = fmaf(e, l, t2s);
      }
      #pragma unroll
      for(int off=1; off<16; off<<=1){
        s1  += __shfl_xor(s1,  off, 64);
        t2s += __shfl_xor(t2s, off, 64);
      }
      if(nc == 0){
        dm[i]=dl; km[i]=kl; Ss[i]=s1; Ts[i]=t2s;
      } else {
        if(dl < dm[i]){                      // strict <: tie keeps old (smaller idx)
          float del = 100.0f*(dl - dm[i]); float al = expf(del);
          Ts[i] = al*(Ts[i] + Ss[i]*del) + t2s;
          Ss[i] = al*Ss[i] + s1;
          dm[i] = dl; km[i] = kl;
        } else {
          float del = 100.0f*(dm[i] - dl); float al = expf(del);
          Ts[i] += al*(t2s + s1*del);
          Ss[i] += al*s1;
        }
      }
    }
  }

  // ---- final per-row writes (one owner thread per row group: tx==0)
  float plogp = 0.f;
  if(tx == 0){
    #pragma unroll
    for(int i=0;i<8;i++){
      int n = m0 + ty*8 + i;
      out[IDX_OFF + n] = (float)km[i];
      sk[ty*8 + i] = km[i];
      atomicAdd(hist + km[i], 1.0f);
      plogp += Ts[i]/Ss[i] - logf(Ss[i]);
    }
  }
  plogp = wsum64(plogp);
  if((t & 63) == 0) atomicAdd(acc_sc + 1, plogp);

  // ---- fused quant gather + mse -------------------------------------------
  __syncthreads();                 // sk[] visible to all waves
  {
    int w = t>>6, lane = t&63;
    int row0 = w*32;
    float mse = 0.f;
    for(int r=0;r<32;r++){
      int n = m0 + row0 + r;
      int k = sk[row0 + r];
      float4 cb4 = *(const float4*)(CB + (size_t)k*DIMS + lane*4);
      float4 x4  = *(const float4*)(X  + (size_t)n*DIMS + lane*4);
      float e0=x4.x-cb4.x, e1=x4.y-cb4.y, e2=x4.z-cb4.z, e3=x4.w-cb4.w;
      mse += e0*e0 + e1*e1 + e2*e2 + e3*e3;
      *reinterpret_cast<float4*>(out + (size_t)n*DIMS + lane*4) = cb4;
    }
    mse = wsum64(mse);
    if(lane==0) atomicAdd(acc_sc+0, mse);
  }
}

// ---------------- finalize scalars (float32) --------------------------------
__global__ __launch_bounds__(256) void finalize_kernel(const float* __restrict__ hist,
                                                       const float* __restrict__ acc_sc,
                                                       float* __restrict__ out){
  __shared__ float red[256];
  int t = threadIdx.x;
  float s = 0.f;
  #pragma unroll
  for(int c=0;c<4;c++){
    float ap = hist[c*256 + t] * (1.0f/32768.0f);   // avg_probs ~ argmin histogram
    s += ap * logf(ap + 1e-5f);
  }
  red[t] = s; __syncthreads();
  for(int off=128; off; off>>=1){
    if(t<off) red[t]+=red[t+off];
    __syncthreads();
  }
  if(t==0){
    float avg_entropy    = -red[0];
    float mse            = acc_sc[0] * (1.0f/8388608.0f);
    float sample_entropy = -(acc_sc[1] * (1.0f/32768.0f));
    float commit = 0.5f*mse*0.25f;
    float cbl    = 0.5f*mse;
    float ent    = (sample_entropy - avg_entropy)*0.1f;
    float vq     = cbl + commit + ent;
    out[SC_OFF+0] = vq;
    out[SC_OFF+1] = commit;
    out[SC_OFF+2] = cbl;
    out[SC_OFF+3] = ent;
  }
}

extern "C" void kernel_launch(void* const* d_in, const int* in_sizes, int n_in,
                              void* d_out, int out_size, void* d_ws, size_t ws_size,
                              hipStream_t stream){
  const float* X  = (const float*)d_in[0];
  const float* CB = (const float*)d_in[1];
  float* out = (float*)d_out;                        // float32 output buffer
  float* hist    = (float*)d_ws;                     // [1024]
  float* acc_sc  = hist + K_CODES;                   // [2]: mse, plogp

  hipMemsetAsync(hist, 0, (K_CODES+2)*sizeof(float), stream);
  fused_argmin_kernel<<<N_ROWS/MT, 256, 0, stream>>>(X, CB, hist, acc_sc, out);
  finalize_kernel    <<<1, 256, 0, stream>>>(hist, acc_sc, out);
}